// Round 6
// baseline (6152.086 us; speedup 1.0000x reference)
//
#include <hip/hip_runtime.h>
#include <hip/hip_fp16.h>

#define NN 200000
#define EE 3200000
#define HID 32
#define HB 16384   // src-degree histogram bins per group (64 KB LDS)
#define HG 13      // bin groups: 13*16384 >= NN
#define HBK 25     // edge slices for degree hist
#define ESL (EE / HBK)

#define DT 512                    // dst-tile size (nodes)
#define NT_D 391                  // ceil(NN/512)
#define NT_S 13                   // src tiles of 16384 nodes
#define NKEY (NT_D * NT_S)        // 5083 buckets
#define KSL 100                   // scatter slices
#define KESL (EE / KSL)           // 32000

// ---------------- fp16 pack helpers (4 halfs <-> float4, 8B memory op) ------

__device__ inline float4 ld_h4(const __half* p) {
    uint2 u = *reinterpret_cast<const uint2*>(p);
    __half2 a = *reinterpret_cast<__half2*>(&u.x);
    __half2 b = *reinterpret_cast<__half2*>(&u.y);
    float2 fa = __half22float2(a), fb = __half22float2(b);
    return make_float4(fa.x, fa.y, fb.x, fb.y);
}

__device__ inline void st_h4(__half* p, float4 v) {
    __half2 a = __floats2half2_rn(v.x, v.y);
    __half2 b = __floats2half2_rn(v.z, v.w);
    uint2 u;
    u.x = *reinterpret_cast<unsigned*>(&a);
    u.y = *reinterpret_cast<unsigned*>(&b);
    *reinterpret_cast<uint2*>(p) = u;
}

// ---------------- src-degree histogram (for dinv; no device atomics) --------

__global__ __launch_bounds__(256) void k_hist(const int* __restrict__ vals,
                                              int* __restrict__ partial) {
    __shared__ int h[HB];
    int b = blockIdx.x / HG, g = blockIdx.x % HG;
    int base = g * HB;
    for (int i = threadIdx.x; i < HB; i += 256) h[i] = 0;
    __syncthreads();
    const int4* p4 = reinterpret_cast<const int4*>(vals + (size_t)b * ESL);
    for (int i = threadIdx.x; i < ESL / 4; i += 256) {
        int4 v = p4[i];
        int a0 = v.x - base, a1 = v.y - base, a2 = v.z - base, a3 = v.w - base;
        if ((unsigned)a0 < HB) atomicAdd(&h[a0], 1);
        if ((unsigned)a1 < HB) atomicAdd(&h[a1], 1);
        if ((unsigned)a2 < HB) atomicAdd(&h[a2], 1);
        if ((unsigned)a3 < HB) atomicAdd(&h[a3], 1);
    }
    __syncthreads();
    int* out = partial + ((size_t)g * HBK + b) * HB;
    for (int i = threadIdx.x; i < HB; i += 256) out[i] = h[i];
}

__global__ void k_hreduce(const int* __restrict__ partial, int* __restrict__ out) {
    int bi = blockIdx.x * 256 + threadIdx.x;
    if (bi >= NN) return;
    int g = bi >> 14, i = bi & (HB - 1);
    const int* p = partial + (size_t)g * HBK * HB + i;
    int s = 0;
#pragma unroll
    for (int b = 0; b < HBK; b++) s += p[(size_t)b << 14];
    out[bi] = s;
}

__global__ void k_dinv(const int* __restrict__ dsrc, float* __restrict__ dinv) {
    int i = blockIdx.x * 256 + threadIdx.x;
    if (i < NN) {
        int d = dsrc[i];
        dinv[i] = d > 0 ? rsqrtf((float)d) : 0.f;
    }
}

// ---------------- bucket build: key = dtile*13 + stile ----------------------

__global__ __launch_bounds__(256) void k_khist(const int* __restrict__ ei,
                                               int* __restrict__ kpart) {
    __shared__ int h[NKEY];
    for (int i = threadIdx.x; i < NKEY; i += 256) h[i] = 0;
    __syncthreads();
    int base = blockIdx.x * KESL;
    for (int i = threadIdx.x; i < KESL; i += 256) {
        int e = base + i;
        int src = ei[e], dst = ei[EE + e];
        atomicAdd(&h[(dst >> 9) * NT_S + (src >> 14)], 1);
    }
    __syncthreads();
    int* outp = kpart + (size_t)blockIdx.x * NKEY;
    for (int i = threadIdx.x; i < NKEY; i += 256) outp[i] = h[i];
}

__global__ void k_btotal(const int* __restrict__ kpart, int* __restrict__ btot) {
    int k = blockIdx.x * 256 + threadIdx.x;
    if (k >= NKEY) return;
    int s = 0;
    for (int b = 0; b < KSL; b++) s += kpart[(size_t)b * NKEY + k];
    btot[k] = s;
}

__global__ void k_bscan(const int* __restrict__ btot, int* __restrict__ bstart) {
    __shared__ int s[256];
    __shared__ int carry;
    if (threadIdx.x == 0) carry = 0;
    __syncthreads();
    for (int base = 0; base < NKEY; base += 256) {
        int k = base + threadIdx.x;
        int v = (k < NKEY) ? btot[k] : 0;
        s[threadIdx.x] = v;
        __syncthreads();
        for (int off = 1; off < 256; off <<= 1) {
            int t = (threadIdx.x >= off) ? s[threadIdx.x - off] : 0;
            __syncthreads();
            s[threadIdx.x] += t;
            __syncthreads();
        }
        int excl = s[threadIdx.x] - v + carry;
        if (k < NKEY) bstart[k] = excl;
        __syncthreads();
        if (threadIdx.x == 0) carry += s[255];
        __syncthreads();
    }
    if (threadIdx.x == 0) bstart[NKEY] = EE;
}

// in-place: kpart[s][k] becomes the global write offset for slice s, bucket k
__global__ void k_soff(int* __restrict__ kpart, const int* __restrict__ bstart) {
    int k = blockIdx.x * 256 + threadIdx.x;
    if (k >= NKEY) return;
    int running = bstart[k];
    for (int s = 0; s < KSL; s++) {
        int t = kpart[(size_t)s * NKEY + k];
        kpart[(size_t)s * NKEY + k] = running;
        running += t;
    }
}

__global__ __launch_bounds__(256) void k_scatter(const int* __restrict__ ei,
                                                 const float* __restrict__ dinv,
                                                 const int* __restrict__ kpart,
                                                 int* __restrict__ epack,
                                                 float* __restrict__ ew) {
    __shared__ int cnt[NKEY];
    for (int i = threadIdx.x; i < NKEY; i += 256) cnt[i] = 0;
    __syncthreads();
    const int* soffp = kpart + (size_t)blockIdx.x * NKEY;
    int base = blockIdx.x * KESL;
    for (int i = threadIdx.x; i < KESL; i += 256) {
        int e = base + i;
        int src = ei[e], dst = ei[EE + e];
        int key = (dst >> 9) * NT_S + (src >> 14);
        int rank = atomicAdd(&cnt[key], 1);
        int pos = soffp[key] + rank;
        epack[pos] = (src << 9) | (dst & 511);
        ew[pos] = -dinv[src] * dinv[dst];
    }
}

// ---------------- input MLP: h = relu(x @ W0 + b0), fp16 out ----------------

__global__ void k_mlp0(const float* __restrict__ x, const float* __restrict__ W0,
                       const float* __restrict__ b0, __half* __restrict__ out) {
    int t = blockIdx.x * 256 + threadIdx.x;   // t = n*32 + o
    int n = t >> 5, o = t & 31;
    if (n < NN) {
        float acc = b0[o];
#pragma unroll
        for (int i = 0; i < 3; i++) acc += x[n * 3 + i] * W0[i * 32 + o];
        out[t] = __float2half(fmaxf(acc, 0.f));
    }
}

// ---------------- propagation: dst-tile block, LDS fp32 accumulation --------
// Edges in bucket order (src-tile ascending within dst-tile) => gathers sweep
// ~1MB L2-resident src windows. 8 lanes/edge, 8B gather/lane = 1 line/edge.

__global__ __launch_bounds__(256) void k_prop_lds(const int* __restrict__ bstart,
                                                  const int* __restrict__ epack,
                                                  const float* __restrict__ ew,
                                                  const __half* __restrict__ x,
                                                  __half* __restrict__ y) {
    __shared__ float acc[DT * 33];   // stride 33: kills power-of-2 bank aliasing
    int tid = threadIdx.x;
    for (int i = tid; i < DT * 33; i += 256) acc[i] = 0.f;
    __syncthreads();
    int d = blockIdx.x;
    int beg = bstart[d * NT_S];
    int end = bstart[(d + 1) * NT_S];
    int c = tid & 7, eo = tid >> 3;       // 8 lanes/edge, 32 edge slots/block
    int c4 = c * 4;
    const __half* xc = x + c4;
    int j = beg + eo;
    for (; j < end - 96; j += 128) {      // 4-way unrolled (MLP=4 gathers)
        int p0 = epack[j +  0], p1 = epack[j + 32];
        int p2 = epack[j + 64], p3 = epack[j + 96];
        float w0 = ew[j +  0], w1 = ew[j + 32];
        float w2 = ew[j + 64], w3 = ew[j + 96];
        float4 v0 = ld_h4(xc + (size_t)(p0 >> 9) * 32);
        float4 v1 = ld_h4(xc + (size_t)(p1 >> 9) * 32);
        float4 v2 = ld_h4(xc + (size_t)(p2 >> 9) * 32);
        float4 v3 = ld_h4(xc + (size_t)(p3 >> 9) * 32);
        float* a0 = acc + (p0 & 511) * 33 + c4;
        float* a1 = acc + (p1 & 511) * 33 + c4;
        float* a2 = acc + (p2 & 511) * 33 + c4;
        float* a3 = acc + (p3 & 511) * 33 + c4;
        atomicAdd(a0 + 0, w0 * v0.x); atomicAdd(a0 + 1, w0 * v0.y);
        atomicAdd(a0 + 2, w0 * v0.z); atomicAdd(a0 + 3, w0 * v0.w);
        atomicAdd(a1 + 0, w1 * v1.x); atomicAdd(a1 + 1, w1 * v1.y);
        atomicAdd(a1 + 2, w1 * v1.z); atomicAdd(a1 + 3, w1 * v1.w);
        atomicAdd(a2 + 0, w2 * v2.x); atomicAdd(a2 + 1, w2 * v2.y);
        atomicAdd(a2 + 2, w2 * v2.z); atomicAdd(a2 + 3, w2 * v2.w);
        atomicAdd(a3 + 0, w3 * v3.x); atomicAdd(a3 + 1, w3 * v3.y);
        atomicAdd(a3 + 2, w3 * v3.z); atomicAdd(a3 + 3, w3 * v3.w);
    }
    for (; j < end; j += 32) {
        int p0 = epack[j];
        float w0 = ew[j];
        float4 v0 = ld_h4(xc + (size_t)(p0 >> 9) * 32);
        float* a0 = acc + (p0 & 511) * 33 + c4;
        atomicAdd(a0 + 0, w0 * v0.x); atomicAdd(a0 + 1, w0 * v0.y);
        atomicAdd(a0 + 2, w0 * v0.z); atomicAdd(a0 + 3, w0 * v0.w);
    }
    __syncthreads();
    int node0 = d * DT;
    for (int i = tid; i < DT * 8; i += 256) {
        int r = i >> 3, cc = i & 7;
        int node = node0 + r;
        if (node < NN) {
            float* a = acc + r * 33 + cc * 4;
            st_h4(y + (size_t)node * 32 + cc * 4,
                  make_float4(a[0], a[1], a[2], a[3]));
        }
    }
}

// ---------------- fused Cheb combine (fp16 I/O, fp32 math) ----------------

__global__ void k_cheb(const __half* T0, const __half* P1, const __half* P2,
                       const __half* res, __half* out,
                       const float* __restrict__ W, const float* __restrict__ b,
                       int do_relu, int has_res) {
    __shared__ float sT0[8][32], sP1[8][32], sP2[8][32], sR[8][32];
    int t = threadIdx.x;
    int nl = t >> 5, o = t & 31;
    int gi = blockIdx.x * 256 + t;
    sT0[nl][o] = __half2float(T0[gi]);
    sP1[nl][o] = __half2float(P1[gi]);
    sP2[nl][o] = __half2float(P2[gi]);
    sR[nl][o] = has_res ? __half2float(res[gi]) : 0.f;
    __syncthreads();
    float acc = b[o] + sR[nl][o];
#pragma unroll
    for (int i = 0; i < 32; i++) {
        float w0 = W[i * 32 + o];
        float w1 = W[1024 + i * 32 + o];
        float w2 = W[2048 + i * 32 + o];
        float t0 = sT0[nl][i];
        acc += t0 * w0 + sP1[nl][i] * w1 + (2.f * sP2[nl][i] - t0) * w2;
    }
    if (do_relu) acc = fmaxf(acc, 0.f);
    out[gi] = __float2half(acc);
}

// ---------------- final head: out = X @ W1 + b1 (fp16 in, fp32 out) ---------

__global__ void k_final(const __half* __restrict__ X, const float* __restrict__ W1,
                        const float* __restrict__ b1, float* __restrict__ out) {
    int n = blockIdx.x * 256 + threadIdx.x;
    if (n < NN) {
        float acc = b1[0];
        const __half* xp = X + (size_t)n * 32;
#pragma unroll
        for (int c = 0; c < 8; c++) {
            float4 v = ld_h4(xp + c * 4);
            acc += v.x * W1[c * 4 + 0] + v.y * W1[c * 4 + 1] +
                   v.z * W1[c * 4 + 2] + v.w * W1[c * 4 + 3];
        }
        out[n] = acc;
    }
}

extern "C" void kernel_launch(void* const* d_in, const int* in_sizes, int n_in,
                              void* d_out, int out_size, void* d_ws, size_t ws_size,
                              hipStream_t stream) {
    const float* x    = (const float*)d_in[0];
    const int*   ei   = (const int*)d_in[1];
    const float* W0   = (const float*)d_in[2];
    const float* b0   = (const float*)d_in[3];
    const float* c11W = (const float*)d_in[4];
    const float* c11b = (const float*)d_in[5];
    const float* c12W = (const float*)d_in[6];
    const float* c12b = (const float*)d_in[7];
    const float* c21W = (const float*)d_in[8];
    const float* c21b = (const float*)d_in[9];
    const float* c22W = (const float*)d_in[10];
    const float* c22b = (const float*)d_in[11];
    const float* W1   = (const float*)d_in[12];
    const float* b1   = (const float*)d_in[13];
    float* out = (float*)d_out;

    char* ws = (char*)d_ws;
    int* dsrc = (int*)ws;     ws += (size_t)NN * 4;
    float* dinv = (float*)ws; ws += (size_t)NN * 4;
    int* partial = (int*)ws;  ws += (size_t)HG * HBK * HB * 4;   // 21.3 MB
    int* kpart = (int*)ws;    ws += (size_t)KSL * NKEY * 4;      // 2.0 MB
    int* btot = (int*)ws;     ws += (size_t)NKEY * 4;
    int* bstart = (int*)ws;   ws += (size_t)(NKEY + 1) * 4;
    int* epack = (int*)ws;    ws += (size_t)EE * 4;              // 12.8 MB
    float* ew = (float*)ws;   ws += (size_t)EE * 4;              // 12.8 MB
    __half* F0 = (__half*)ws; ws += (size_t)NN * HID * 2;
    __half* F1 = (__half*)ws; ws += (size_t)NN * HID * 2;
    __half* P1 = (__half*)ws; ws += (size_t)NN * HID * 2;
    __half* P2 = (__half*)ws; ws += (size_t)NN * HID * 2;

    // degree -> dinv
    k_hist<<<HG * HBK, 256, 0, stream>>>(ei, partial);
    k_hreduce<<<(NN + 255) / 256, 256, 0, stream>>>(partial, dsrc);
    k_dinv<<<(NN + 255) / 256, 256, 0, stream>>>(dsrc, dinv);

    // bucketed edge list (counting sort by (dtile, stile); no device atomics)
    k_khist<<<KSL, 256, 0, stream>>>(ei, kpart);
    k_btotal<<<(NKEY + 255) / 256, 256, 0, stream>>>(kpart, btot);
    k_bscan<<<1, 256, 0, stream>>>(btot, bstart);
    k_soff<<<(NKEY + 255) / 256, 256, 0, stream>>>(kpart, bstart);
    k_scatter<<<KSL, 256, 0, stream>>>(ei, dinv, kpart, epack, ew);

    k_mlp0<<<NN * HID / 256, 256, 0, stream>>>(x, W0, b0, F0);

    auto conv = [&](const __half* T0, const __half* res, __half* outb,
                    const float* W, const float* b, int relu, int has_res) {
        k_prop_lds<<<NT_D, 256, 0, stream>>>(bstart, epack, ew, T0, P1);
        k_prop_lds<<<NT_D, 256, 0, stream>>>(bstart, epack, ew, P1, P2);
        k_cheb<<<NN / 8, 256, 0, stream>>>(T0, P1, P2, res, outb, W, b, relu, has_res);
    };

    conv(F0, nullptr, F1, c11W, c11b, 1, 0);   // block1 conv1: relu
    conv(F1, F0,      F0, c12W, c12b, 1, 1);   // block1 conv2: +res, relu
    conv(F0, nullptr, F1, c21W, c21b, 1, 0);   // block2 conv1: relu
    conv(F1, F0,      F0, c22W, c22b, 1, 1);   // block2 conv2: +res, relu

    k_final<<<(NN + 255) / 256, 256, 0, stream>>>(F0, W1, b1, out);
}

// Round 7
// 1103.883 us; speedup vs baseline: 5.5731x; 5.5731x over previous
//
#include <hip/hip_runtime.h>
#include <hip/hip_fp16.h>

#define NN 200000
#define EE 3200000
#define HID 32
#define HB 16384   // src-degree histogram bins per group (64 KB LDS)
#define HG 13      // bin groups: 13*16384 >= NN
#define HBK 25     // edge slices for degree hist
#define ESL (EE / HBK)

#define TN 64                 // dst-tile nodes
#define NT 3125               // NN / 64 exactly
#define KSL 100               // sort slices
#define KESL (EE / KSL)       // 32000

// ---------------- fp16 pack helpers (4 halfs <-> float4, 8B memory op) ------

__device__ inline float4 ld_h4(const __half* p) {
    uint2 u = *reinterpret_cast<const uint2*>(p);
    __half2 a = *reinterpret_cast<__half2*>(&u.x);
    __half2 b = *reinterpret_cast<__half2*>(&u.y);
    float2 fa = __half22float2(a), fb = __half22float2(b);
    return make_float4(fa.x, fa.y, fb.x, fb.y);
}

__device__ inline void st_h4(__half* p, float4 v) {
    __half2 a = __floats2half2_rn(v.x, v.y);
    __half2 b = __floats2half2_rn(v.z, v.w);
    uint2 u;
    u.x = *reinterpret_cast<unsigned*>(&a);
    u.y = *reinterpret_cast<unsigned*>(&b);
    *reinterpret_cast<uint2*>(p) = u;
}

// ---------------- src-degree histogram (for dinv; no device atomics) --------

__global__ __launch_bounds__(256) void k_hist(const int* __restrict__ vals,
                                              int* __restrict__ partial) {
    __shared__ int h[HB];
    int b = blockIdx.x / HG, g = blockIdx.x % HG;
    int base = g * HB;
    for (int i = threadIdx.x; i < HB; i += 256) h[i] = 0;
    __syncthreads();
    const int4* p4 = reinterpret_cast<const int4*>(vals + (size_t)b * ESL);
    for (int i = threadIdx.x; i < ESL / 4; i += 256) {
        int4 v = p4[i];
        int a0 = v.x - base, a1 = v.y - base, a2 = v.z - base, a3 = v.w - base;
        if ((unsigned)a0 < HB) atomicAdd(&h[a0], 1);
        if ((unsigned)a1 < HB) atomicAdd(&h[a1], 1);
        if ((unsigned)a2 < HB) atomicAdd(&h[a2], 1);
        if ((unsigned)a3 < HB) atomicAdd(&h[a3], 1);
    }
    __syncthreads();
    int* out = partial + ((size_t)g * HBK + b) * HB;
    for (int i = threadIdx.x; i < HB; i += 256) out[i] = h[i];
}

__global__ void k_hreduce(const int* __restrict__ partial, int* __restrict__ out) {
    int bi = blockIdx.x * 256 + threadIdx.x;
    if (bi >= NN) return;
    int g = bi >> 14, i = bi & (HB - 1);
    const int* p = partial + (size_t)g * HBK * HB + i;
    int s = 0;
#pragma unroll
    for (int b = 0; b < HBK; b++) s += p[(size_t)b << 14];
    out[bi] = s;
}

__global__ void k_dinv(const int* __restrict__ dsrc, float* __restrict__ dinv) {
    int i = blockIdx.x * 256 + threadIdx.x;
    if (i < NN) {
        int d = dsrc[i];
        dinv[i] = d > 0 ? rsqrtf((float)d) : 0.f;
    }
}

// ---------------- dst-tile counting sort (atomic-free at device scope) ------
// key = dst >> 6 (3125 tiles of 64 nodes; NN = 3125*64 exactly)

__global__ __launch_bounds__(256) void k_khist(const int* __restrict__ ei,
                                               int* __restrict__ kpart) {
    __shared__ int h[NT];
    for (int i = threadIdx.x; i < NT; i += 256) h[i] = 0;
    __syncthreads();
    int base = blockIdx.x * KESL;
    for (int i = threadIdx.x; i < KESL; i += 256)
        atomicAdd(&h[ei[EE + base + i] >> 6], 1);
    __syncthreads();
    int* outp = kpart + (size_t)blockIdx.x * NT;
    for (int i = threadIdx.x; i < NT; i += 256) outp[i] = h[i];
}

__global__ void k_btotal(const int* __restrict__ kpart, int* __restrict__ btot) {
    int k = blockIdx.x * 256 + threadIdx.x;
    if (k >= NT) return;
    int s = 0;
    for (int b = 0; b < KSL; b++) s += kpart[(size_t)b * NT + k];
    btot[k] = s;
}

__global__ void k_bscan(const int* __restrict__ btot, int* __restrict__ bstart) {
    __shared__ int s[256];
    __shared__ int carry;
    if (threadIdx.x == 0) carry = 0;
    __syncthreads();
    for (int base = 0; base < NT; base += 256) {
        int k = base + threadIdx.x;
        int v = (k < NT) ? btot[k] : 0;
        s[threadIdx.x] = v;
        __syncthreads();
        for (int off = 1; off < 256; off <<= 1) {
            int t = (threadIdx.x >= off) ? s[threadIdx.x - off] : 0;
            __syncthreads();
            s[threadIdx.x] += t;
            __syncthreads();
        }
        int excl = s[threadIdx.x] - v + carry;
        if (k < NT) bstart[k] = excl;
        __syncthreads();
        if (threadIdx.x == 0) carry += s[255];
        __syncthreads();
    }
    if (threadIdx.x == 0) bstart[NT] = EE;
}

// in-place: kpart[s][k] becomes the global write offset for slice s, tile k
__global__ void k_soff(int* __restrict__ kpart, const int* __restrict__ bstart) {
    int k = blockIdx.x * 256 + threadIdx.x;
    if (k >= NT) return;
    int running = bstart[k];
    for (int s = 0; s < KSL; s++) {
        int t = kpart[(size_t)s * NT + k];
        kpart[(size_t)s * NT + k] = running;
        running += t;
    }
}

__global__ __launch_bounds__(256) void k_scatter(const int* __restrict__ ei,
                                                 const float* __restrict__ dinv,
                                                 const int* __restrict__ kpart,
                                                 int2* __restrict__ ebkt) {
    __shared__ int cnt[NT];
    for (int i = threadIdx.x; i < NT; i += 256) cnt[i] = 0;
    __syncthreads();
    const int* soffp = kpart + (size_t)blockIdx.x * NT;
    int base = blockIdx.x * KESL;
    for (int i = threadIdx.x; i < KESL; i += 256) {
        int e = base + i;
        int src = ei[e], dst = ei[EE + e];
        int key = dst >> 6;
        int rank = atomicAdd(&cnt[key], 1);
        float w = -dinv[src] * dinv[dst];
        ebkt[soffp[key] + rank] = make_int2((src << 6) | (dst & 63),
                                            __float_as_int(w));
    }
}

// ---------------- finish sort within tile: exact-dst CSR + rowptr -----------

__global__ __launch_bounds__(256) void k_fill2(const int* __restrict__ bstart,
                                               const int2* __restrict__ ebkt,
                                               int* __restrict__ rowptr,
                                               int2* __restrict__ csr) {
    __shared__ int deg[TN], excl[TN], rank[TN];
    int t = blockIdx.x, tid = threadIdx.x;
    int beg = bstart[t], end = bstart[t + 1];
    if (tid < TN) { deg[tid] = 0; rank[tid] = 0; }
    __syncthreads();
    for (int j = beg + tid; j < end; j += 256)
        atomicAdd(&deg[ebkt[j].x & 63], 1);
    __syncthreads();
    if (tid == 0) {
        int s = 0;
#pragma unroll
        for (int k = 0; k < TN; k++) { excl[k] = s; s += deg[k]; }
    }
    __syncthreads();
    if (tid < TN) rowptr[t * TN + tid] = beg + excl[tid];
    if (t == NT - 1 && tid == 0) rowptr[NN] = EE;
    for (int j = beg + tid; j < end; j += 256) {
        int2 e = ebkt[j];
        int local = e.x & 63;
        int r = atomicAdd(&rank[local], 1);
        csr[beg + excl[local] + r] = make_int2(e.x >> 6, e.y);
    }
}

// ---------------- input MLP: h = relu(x @ W0 + b0), fp16 out ----------------

__global__ void k_mlp0(const float* __restrict__ x, const float* __restrict__ W0,
                       const float* __restrict__ b0, __half* __restrict__ out) {
    int t = blockIdx.x * 256 + threadIdx.x;   // t = n*32 + o
    int n = t >> 5, o = t & 31;
    if (n < NN) {
        float acc = b0[o];
#pragma unroll
        for (int i = 0; i < 3; i++) acc += x[n * 3 + i] * W0[i * 32 + o];
        out[t] = __float2half(fmaxf(acc, 0.f));
    }
}

// ---------------- propagation (CSR, gather-only, fp16 features) -------------
// 8 threads/node, 4 halfs (8B) per thread => 1 cache line per edge row.

__global__ __launch_bounds__(256) void k_prop_csr(const int* __restrict__ rowptr,
                                                  const int2* __restrict__ csr,
                                                  const __half* __restrict__ x,
                                                  __half* __restrict__ y) {
    int t = blockIdx.x * 256 + threadIdx.x;
    int n = t >> 3, c = t & 7;
    if (n >= NN) return;
    int beg = rowptr[n], end = rowptr[n + 1];
    float4 acc = make_float4(0.f, 0.f, 0.f, 0.f);
    int j = beg;
    const __half* xc = x + (size_t)c * 4;
    for (; j + 8 <= end; j += 8) {
        int2 e0 = csr[j + 0], e1 = csr[j + 1], e2 = csr[j + 2], e3 = csr[j + 3];
        int2 e4 = csr[j + 4], e5 = csr[j + 5], e6 = csr[j + 6], e7 = csr[j + 7];
        float4 v0 = ld_h4(xc + (size_t)e0.x * 32);
        float4 v1 = ld_h4(xc + (size_t)e1.x * 32);
        float4 v2 = ld_h4(xc + (size_t)e2.x * 32);
        float4 v3 = ld_h4(xc + (size_t)e3.x * 32);
        float4 v4 = ld_h4(xc + (size_t)e4.x * 32);
        float4 v5 = ld_h4(xc + (size_t)e5.x * 32);
        float4 v6 = ld_h4(xc + (size_t)e6.x * 32);
        float4 v7 = ld_h4(xc + (size_t)e7.x * 32);
        float w0 = __int_as_float(e0.y), w1 = __int_as_float(e1.y);
        float w2 = __int_as_float(e2.y), w3 = __int_as_float(e3.y);
        float w4 = __int_as_float(e4.y), w5 = __int_as_float(e5.y);
        float w6 = __int_as_float(e6.y), w7 = __int_as_float(e7.y);
        acc.x += w0 * v0.x + w1 * v1.x + w2 * v2.x + w3 * v3.x
               + w4 * v4.x + w5 * v5.x + w6 * v6.x + w7 * v7.x;
        acc.y += w0 * v0.y + w1 * v1.y + w2 * v2.y + w3 * v3.y
               + w4 * v4.y + w5 * v5.y + w6 * v6.y + w7 * v7.y;
        acc.z += w0 * v0.z + w1 * v1.z + w2 * v2.z + w3 * v3.z
               + w4 * v4.z + w5 * v5.z + w6 * v6.z + w7 * v7.z;
        acc.w += w0 * v0.w + w1 * v1.w + w2 * v2.w + w3 * v3.w
               + w4 * v4.w + w5 * v5.w + w6 * v6.w + w7 * v7.w;
    }
    for (; j + 4 <= end; j += 4) {
        int2 e0 = csr[j + 0], e1 = csr[j + 1], e2 = csr[j + 2], e3 = csr[j + 3];
        float4 v0 = ld_h4(xc + (size_t)e0.x * 32);
        float4 v1 = ld_h4(xc + (size_t)e1.x * 32);
        float4 v2 = ld_h4(xc + (size_t)e2.x * 32);
        float4 v3 = ld_h4(xc + (size_t)e3.x * 32);
        float w0 = __int_as_float(e0.y), w1 = __int_as_float(e1.y);
        float w2 = __int_as_float(e2.y), w3 = __int_as_float(e3.y);
        acc.x += w0 * v0.x + w1 * v1.x + w2 * v2.x + w3 * v3.x;
        acc.y += w0 * v0.y + w1 * v1.y + w2 * v2.y + w3 * v3.y;
        acc.z += w0 * v0.z + w1 * v1.z + w2 * v2.z + w3 * v3.z;
        acc.w += w0 * v0.w + w1 * v1.w + w2 * v2.w + w3 * v3.w;
    }
    for (; j < end; j++) {
        int2 e = csr[j];
        float w = __int_as_float(e.y);
        float4 v = ld_h4(xc + (size_t)e.x * 32);
        acc.x += w * v.x; acc.y += w * v.y; acc.z += w * v.z; acc.w += w * v.w;
    }
    st_h4(y + (size_t)n * 32 + c * 4, acc);
}

// ---------------- fused Cheb combine (fp16 I/O, fp32 math) ----------------

__global__ void k_cheb(const __half* T0, const __half* P1, const __half* P2,
                       const __half* res, __half* out,
                       const float* __restrict__ W, const float* __restrict__ b,
                       int do_relu, int has_res) {
    __shared__ float sT0[8][32], sP1[8][32], sP2[8][32], sR[8][32];
    int t = threadIdx.x;
    int nl = t >> 5, o = t & 31;
    int gi = blockIdx.x * 256 + t;
    sT0[nl][o] = __half2float(T0[gi]);
    sP1[nl][o] = __half2float(P1[gi]);
    sP2[nl][o] = __half2float(P2[gi]);
    sR[nl][o] = has_res ? __half2float(res[gi]) : 0.f;
    __syncthreads();
    float acc = b[o] + sR[nl][o];
#pragma unroll
    for (int i = 0; i < 32; i++) {
        float w0 = W[i * 32 + o];
        float w1 = W[1024 + i * 32 + o];
        float w2 = W[2048 + i * 32 + o];
        float t0 = sT0[nl][i];
        acc += t0 * w0 + sP1[nl][i] * w1 + (2.f * sP2[nl][i] - t0) * w2;
    }
    if (do_relu) acc = fmaxf(acc, 0.f);
    out[gi] = __float2half(acc);
}

// ---------------- final head: out = X @ W1 + b1 (fp16 in, fp32 out) ---------

__global__ void k_final(const __half* __restrict__ X, const float* __restrict__ W1,
                        const float* __restrict__ b1, float* __restrict__ out) {
    int n = blockIdx.x * 256 + threadIdx.x;
    if (n < NN) {
        float acc = b1[0];
        const __half* xp = X + (size_t)n * 32;
#pragma unroll
        for (int c = 0; c < 8; c++) {
            float4 v = ld_h4(xp + c * 4);
            acc += v.x * W1[c * 4 + 0] + v.y * W1[c * 4 + 1] +
                   v.z * W1[c * 4 + 2] + v.w * W1[c * 4 + 3];
        }
        out[n] = acc;
    }
}

extern "C" void kernel_launch(void* const* d_in, const int* in_sizes, int n_in,
                              void* d_out, int out_size, void* d_ws, size_t ws_size,
                              hipStream_t stream) {
    const float* x    = (const float*)d_in[0];
    const int*   ei   = (const int*)d_in[1];
    const float* W0   = (const float*)d_in[2];
    const float* b0   = (const float*)d_in[3];
    const float* c11W = (const float*)d_in[4];
    const float* c11b = (const float*)d_in[5];
    const float* c12W = (const float*)d_in[6];
    const float* c12b = (const float*)d_in[7];
    const float* c21W = (const float*)d_in[8];
    const float* c21b = (const float*)d_in[9];
    const float* c22W = (const float*)d_in[10];
    const float* c22b = (const float*)d_in[11];
    const float* W1   = (const float*)d_in[12];
    const float* b1   = (const float*)d_in[13];
    float* out = (float*)d_out;

    char* ws = (char*)d_ws;
    int* dsrc = (int*)ws;     ws += (size_t)NN * 4;
    float* dinv = (float*)ws; ws += (size_t)NN * 4;
    int* rowptr = (int*)ws;   ws += (size_t)(NN + 1) * 4;
    int* partial = (int*)ws;  ws += (size_t)HG * HBK * HB * 4;   // 21.3 MB
    int* kpart = (int*)ws;    ws += (size_t)KSL * NT * 4;        // 1.25 MB
    int* btot = (int*)ws;     ws += (size_t)NT * 4;
    int* bstart = (int*)ws;   ws += (size_t)(NT + 1) * 4;
    ws = (char*)(((uintptr_t)ws + 15) & ~(uintptr_t)15);
    int2* ebkt = (int2*)ws;   ws += (size_t)EE * 8;              // 25.6 MB
    int2* csr = (int2*)ws;    ws += (size_t)EE * 8;              // 25.6 MB
    __half* F0 = (__half*)ws; ws += (size_t)NN * HID * 2;
    __half* F1 = (__half*)ws; ws += (size_t)NN * HID * 2;
    __half* P1 = (__half*)ws; ws += (size_t)NN * HID * 2;
    __half* P2 = (__half*)ws; ws += (size_t)NN * HID * 2;

    // src degrees -> dinv
    k_hist<<<HG * HBK, 256, 0, stream>>>(ei, partial);
    k_hreduce<<<(NN + 255) / 256, 256, 0, stream>>>(partial, dsrc);
    k_dinv<<<(NN + 255) / 256, 256, 0, stream>>>(dsrc, dinv);

    // dst-tile counting sort -> exact-dst CSR (no device atomics anywhere)
    k_khist<<<KSL, 256, 0, stream>>>(ei, kpart);
    k_btotal<<<(NT + 255) / 256, 256, 0, stream>>>(kpart, btot);
    k_bscan<<<1, 256, 0, stream>>>(btot, bstart);
    k_soff<<<(NT + 255) / 256, 256, 0, stream>>>(kpart, bstart);
    k_scatter<<<KSL, 256, 0, stream>>>(ei, dinv, kpart, ebkt);
    k_fill2<<<NT, 256, 0, stream>>>(bstart, ebkt, rowptr, csr);

    k_mlp0<<<NN * HID / 256, 256, 0, stream>>>(x, W0, b0, F0);

    auto conv = [&](const __half* T0, const __half* res, __half* outb,
                    const float* W, const float* b, int relu, int has_res) {
        k_prop_csr<<<NN * 8 / 256, 256, 0, stream>>>(rowptr, csr, T0, P1);
        k_prop_csr<<<NN * 8 / 256, 256, 0, stream>>>(rowptr, csr, P1, P2);
        k_cheb<<<NN / 8, 256, 0, stream>>>(T0, P1, P2, res, outb, W, b, relu, has_res);
    };

    conv(F0, nullptr, F1, c11W, c11b, 1, 0);   // block1 conv1: relu
    conv(F1, F0,      F0, c12W, c12b, 1, 1);   // block1 conv2: +res, relu
    conv(F0, nullptr, F1, c21W, c21b, 1, 0);   // block2 conv1: relu
    conv(F1, F0,      F0, c22W, c22b, 1, 1);   // block2 conv2: +res, relu

    k_final<<<(NN + 255) / 256, 256, 0, stream>>>(F0, W1, b1, out);
}